// Round 17
// baseline (112.729 us; speedup 1.0000x reference)
//
#include <hip/hip_runtime.h>
#include <stdint.h>

// ---------- types ----------
typedef __attribute__((ext_vector_type(8))) __bf16 fragAB;   // 8 bf16 = 4 VGPR
typedef __attribute__((ext_vector_type(4))) float f32x4;
typedef __attribute__((ext_vector_type(16))) float f32x16;
typedef __attribute__((ext_vector_type(4))) unsigned int u32x4;

__device__ __forceinline__ unsigned short f2bf(float f) {
    union { float f; unsigned int u; } v; v.f = f;
    unsigned int u = v.u + 0x7fffu + ((v.u >> 16) & 1u);   // RNE
    return (unsigned short)(u >> 16);
}

__device__ __forceinline__ f32x4 MFMA16(fragAB a, fragAB b, f32x4 c) {
    return __builtin_amdgcn_mfma_f32_16x16x32_bf16(a, b, c, 0, 0, 0);
}
__device__ __forceinline__ f32x16 MFMA32(fragAB a, fragAB b, f32x16 c) {
    return __builtin_amdgcn_mfma_f32_32x32x16_bf16(a, b, c, 0, 0, 0);
}

// async global->LDS, 16B per lane; LDS dest = wave-uniform base + lane*16
__device__ __forceinline__ void gl16(const void* g, void* l) {
    __builtin_amdgcn_global_load_lds((const __attribute__((address_space(1))) void*)g,
                                     (__attribute__((address_space(3))) void*)l, 16, 0, 0);
}

__device__ __forceinline__ float fsin_rev(float rev) {   // sin(2*pi*rev)
    float r; asm("v_sin_f32 %0, %1" : "=v"(r) : "v"(rev)); return r;
}
__device__ __forceinline__ unsigned int cvtpk(float lo, float hi) {  // 2xbf16 RNE
    unsigned int r; asm("v_cvt_pk_bf16_f32 %0, %1, %2" : "=v"(r) : "v"(lo), "v"(hi)); return r;
}
__device__ __forceinline__ void swap32(unsigned int& a, unsigned int& b) {
    // exchanges a's lanes 32-63 with b's lanes 0-31
    asm volatile("v_permlane32_swap_b32 %0, %1" : "+v"(a), "+v"(b));
}

#define SIN_SC 0.5968310366f   // 3.75 / (2*pi)

// ---------- fused fp32 -> bf16 convert (x + 4 weights in one launch) ----------
__global__ __launch_bounds__(256) void cvt_all(
    const float* __restrict__ x,  const float* __restrict__ wq, const float* __restrict__ wk,
    const float* __restrict__ wv, const float* __restrict__ wo,
    unsigned short* __restrict__ xb,  unsigned short* __restrict__ wqb, unsigned short* __restrict__ wkb,
    unsigned short* __restrict__ wvb, unsigned short* __restrict__ wob)
{
    const int bid = blockIdx.x;
    const float* s; unsigned short* d; int off;
    if (bid < 4096)      { s = x;  d = xb;  off = bid; }
    else if (bid < 5120) { s = wq; d = wqb; off = bid - 4096; }
    else if (bid < 6144) { s = wk; d = wkb; off = bid - 5120; }
    else if (bid < 7168) { s = wv; d = wvb; off = bid - 6144; }
    else                 { s = wo; d = wob; off = bid - 7168; }
    const int i = (off * 256 + threadIdx.x) * 4;
    float4 f = *(const float4*)(s + i);
    ushort4 o;
    o.x = f2bf(f.x); o.y = f2bf(f.y); o.z = f2bf(f.z); o.w = f2bf(f.w);
    *(ushort4*)(d + i) = o;
}

// ---------- GEMM (m97 structure, 128x128): Q/K/V projections ----------
// z=0: Q row-major bf16 (unscaled). z=1: Kshuf. z=2: Vshuf (frag order).
__global__ __launch_bounds__(256, 3)
void gemm_k(const unsigned short* __restrict__ A,
            const unsigned short* __restrict__ W0, const unsigned short* __restrict__ W1,
            const unsigned short* __restrict__ W2,
            const float* __restrict__ b0, const float* __restrict__ b1, const float* __restrict__ b2,
            void* o0, void* o1, void* o2)
{
    __shared__ unsigned short As[8192];   // [128][64] linear, 16KB
    __shared__ unsigned short Ws[8192];

    const int z = blockIdx.z;
    const unsigned short* W = z == 0 ? W0 : (z == 1 ? W1 : W2);
    const float* bias        = z == 0 ? b0 : (z == 1 ? b1 : b2);
    void* out                = z == 0 ? o0 : (z == 1 ? o1 : o2);

    const int t = threadIdx.x;
    const int lane = t & 63;
    const int g = lane >> 4;
    const int c = lane & 15;
    const int w = t >> 6;
    const int wm = (w >> 1) * 64;
    const int wn = (w & 1) * 64;
    const int m0 = blockIdx.y * 128;
    const int n0 = blockIdx.x * 128;

    const int srow = lane >> 3;
    const int scol = (lane & 7) * 8;

    const f32x4 zz = {0.f, 0.f, 0.f, 0.f};
    f32x4 acc[4][4];
#pragma unroll
    for (int mi = 0; mi < 4; ++mi)
#pragma unroll
        for (int ni = 0; ni < 4; ++ni) acc[mi][ni] = zz;

    for (int kt = 0; kt < 16; ++kt) {
        const int k0 = kt * 64;
#pragma unroll
        for (int r = 0; r < 4; ++r) {
            gl16(A + (size_t)(m0 + 32 * w + 8 * r + srow) * 1024 + k0 + scol,
                 (unsigned short*)As + (w * 4 + r) * 512);
            gl16(W + (size_t)(n0 + 32 * w + 8 * r + srow) * 1024 + k0 + scol,
                 (unsigned short*)Ws + (w * 4 + r) * 512);
        }
        __syncthreads();
#pragma unroll
        for (int kk = 0; kk < 2; ++kk) {
            fragAB af[4], bfr[4];
#pragma unroll
            for (int mi = 0; mi < 4; ++mi)
                af[mi] = *(const fragAB*)((char*)As + (wm + mi * 16 + c) * 128 + kk * 64 + g * 16);
#pragma unroll
            for (int ni = 0; ni < 4; ++ni)
                bfr[ni] = *(const fragAB*)((char*)Ws + (wn + ni * 16 + c) * 128 + kk * 64 + g * 16);
#pragma unroll
            for (int mi = 0; mi < 4; ++mi)
#pragma unroll
                for (int ni = 0; ni < 4; ++ni)
                    acc[mi][ni] = MFMA16(af[mi], bfr[ni], acc[mi][ni]);
        }
        __syncthreads();
    }

    float bv[4];
#pragma unroll
    for (int ni = 0; ni < 4; ++ni) bv[ni] = bias[n0 + wn + ni * 16 + c];

    if (z == 0) {                                // Q: row-major bf16 (unscaled)
        unsigned short* C = (unsigned short*)out;
#pragma unroll
        for (int mi = 0; mi < 4; ++mi)
#pragma unroll
            for (int ni = 0; ni < 4; ++ni)
#pragma unroll
                for (int j = 0; j < 4; ++j) {
                    const int grow = m0 + wm + mi * 16 + g * 4 + j;
                    const int gcol = n0 + wn + ni * 16 + c;
                    C[(size_t)grow * 1024 + gcol] = f2bf(acc[mi][ni][j] + bv[ni]);
                }
    } else if (z == 1) {                         // Kshuf scatter (2B stores)
        unsigned short* Ksh = (unsigned short*)out;
#pragma unroll
        for (int mi = 0; mi < 4; ++mi) {
            const int s0 = m0 + wm + mi * 16 + g * 4;
            const int b_ = s0 >> 11, sr = s0 & 2047;
            const int kb = sr >> 6, kbl = (sr >> 5) & 1;
            const int l31b = (mi & 1) * 16 + g * 4;
#pragma unroll
            for (int ni = 0; ni < 4; ++ni) {
                const int n = n0 + wn + ni * 16 + c;
                const int h_ = n >> 6, d = n & 63;
                const int ds = d >> 4, e = d & 7, lhalf = (d >> 3) & 1;
                const size_t base =
                    ((((size_t)(b_ * 16 + h_) * 32 + kb) * 2 + kbl) * 4 + ds) * 512
                    + lhalf * 256 + (size_t)l31b * 8 + e;
#pragma unroll
                for (int j = 0; j < 4; ++j)
                    Ksh[base + j * 8] = f2bf(acc[mi][ni][j] + bv[ni]);
            }
        }
    } else {                                     // Vshuf scatter (8B stores)
        unsigned short* Vsh = (unsigned short*)out;
#pragma unroll
        for (int mi = 0; mi < 4; ++mi) {
            const int s0 = m0 + wm + mi * 16 + g * 4;
            const int b_ = s0 >> 11, sr = s0 & 2047;
            const int kb = sr >> 6;
            const int kslice = mi;               // (mi*16+g*4)>>4
            const int khalf = (g >> 1) & 1;
            const int e0 = (g & 1) * 4;
#pragma unroll
            for (int ni = 0; ni < 4; ++ni) {
                const int n = n0 + wn + ni * 16 + c;
                const int h_ = n >> 6;
                const int nei = ni >> 1;
                const int l31 = (ni & 1) * 16 + c;
                const size_t base =
                    ((((size_t)(b_ * 16 + h_) * 32 + kb) * 4 + kslice) * 2 + nei) * 512
                    + (size_t)(khalf * 32 + l31) * 8 + e0;
                ushort4 pk;
                pk.x = f2bf(acc[mi][ni][0] + bv[ni]);
                pk.y = f2bf(acc[mi][ni][1] + bv[ni]);
                pk.z = f2bf(acc[mi][ni][2] + bv[ni]);
                pk.w = f2bf(acc[mi][ni][3] + bv[ni]);
                *(ushort4*)(Vsh + base) = pk;
            }
        }
    }
}

// ---------- GEMM 64x128 tile, fp32 out: final projection ----------
__global__ __launch_bounds__(256, 4)
void gemm64(const unsigned short* __restrict__ A,
            const unsigned short* __restrict__ W,
            const float* __restrict__ bias, float* __restrict__ out)
{
    __shared__ unsigned short As[4096];   // [64][64]  8KB
    __shared__ unsigned short Ws[8192];   // [128][64] 16KB

    const int t = threadIdx.x;
    const int lane = t & 63;
    const int g = lane >> 4;
    const int c = lane & 15;
    const int w = t >> 6;
    const int wm = (w >> 1) * 32;
    const int wn = (w & 1) * 64;
    const int m0 = blockIdx.y * 64;
    const int n0 = blockIdx.x * 128;

    const int srow = lane >> 3;
    const int scol = (lane & 7) * 8;

    const f32x4 zz = {0.f, 0.f, 0.f, 0.f};
    f32x4 acc[2][4];
#pragma unroll
    for (int mi = 0; mi < 2; ++mi)
#pragma unroll
        for (int ni = 0; ni < 4; ++ni) acc[mi][ni] = zz;

    for (int kt = 0; kt < 16; ++kt) {
        const int k0 = kt * 64;
        gl16(A + (size_t)(m0 + 16 * w + srow) * 1024 + k0 + scol,
             (unsigned short*)As + (2 * w) * 512);
        gl16(A + (size_t)(m0 + 16 * w + 8 + srow) * 1024 + k0 + scol,
             (unsigned short*)As + (2 * w + 1) * 512);
#pragma unroll
        for (int r = 0; r < 4; ++r)
            gl16(W + (size_t)(n0 + 32 * w + 8 * r + srow) * 1024 + k0 + scol,
                 (unsigned short*)Ws + (w * 4 + r) * 512);
        __syncthreads();
#pragma unroll
        for (int kk = 0; kk < 2; ++kk) {
            fragAB af[2], bfr[4];
#pragma unroll
            for (int mi = 0; mi < 2; ++mi)
                af[mi] = *(const fragAB*)((char*)As + (wm + mi * 16 + c) * 128 + kk * 64 + g * 16);
#pragma unroll
            for (int ni = 0; ni < 4; ++ni)
                bfr[ni] = *(const fragAB*)((char*)Ws + (wn + ni * 16 + c) * 128 + kk * 64 + g * 16);
#pragma unroll
            for (int mi = 0; mi < 2; ++mi)
#pragma unroll
                for (int ni = 0; ni < 4; ++ni)
                    acc[mi][ni] = MFMA16(af[mi], bfr[ni], acc[mi][ni]);
        }
        __syncthreads();
    }

#pragma unroll
    for (int ni = 0; ni < 4; ++ni) {
        const float bv = bias[n0 + wn + ni * 16 + c];
#pragma unroll
        for (int mi = 0; mi < 2; ++mi)
#pragma unroll
            for (int j = 0; j < 4; ++j) {
                const int grow = m0 + wm + mi * 16 + g * 4 + j;
                const int gcol = n0 + wn + ni * 16 + c;
                out[(size_t)grow * 1024 + gcol] = acc[mi][ni][j] + bv;
            }
    }
}

// ---------- partial-O sum (in-place): AO = P0 + AO (bf16 in/out, f32 add) ----------
__global__ __launch_bounds__(256)
void add_bf16(const unsigned short* __restrict__ P0, unsigned short* __restrict__ AO)
{
    const int i = (blockIdx.x * 256 + threadIdx.x) * 8;   // 4.19M elems / 8
    uint4 a = *(const uint4*)(P0 + i);
    uint4 c = *(const uint4*)(AO + i);
    union { unsigned int u; float f; } al, ah, cl, ch;
    uint4 o;
    al.u = a.x << 16; ah.u = a.x & 0xffff0000u; cl.u = c.x << 16; ch.u = c.x & 0xffff0000u;
    o.x = cvtpk(al.f + cl.f, ah.f + ch.f);
    al.u = a.y << 16; ah.u = a.y & 0xffff0000u; cl.u = c.y << 16; ch.u = c.y & 0xffff0000u;
    o.y = cvtpk(al.f + cl.f, ah.f + ch.f);
    al.u = a.z << 16; ah.u = a.z & 0xffff0000u; cl.u = c.z << 16; ch.u = c.z & 0xffff0000u;
    o.z = cvtpk(al.f + cl.f, ah.f + ch.f);
    al.u = a.w << 16; ah.u = a.w & 0xffff0000u; cl.u = c.w << 16; ch.u = c.w & 0xffff0000u;
    o.w = cvtpk(al.f + cl.f, ah.f + ch.f);
    *(uint4*)(AO + i) = o;
}

// ---------- fused sine attention v9d: k-split x2, 32KB LDS (two-pass reduce) ----------
// QBLK=256, 8 waves = 4 q-slices(64 rows) x 2 k-halves. Grid 512 = (b,h,qb,kh).
// LDS cut 64->32KB (reduce in 2 passes over qi) to unblock 2-blocks/CU residency:
// R8 (32KB) is the only config that measured ~30% occupancy. Body unchanged (R10).
__global__ __launch_bounds__(512, 2)
void attn_kernel(const unsigned short* __restrict__ Qg,
                 const unsigned short* __restrict__ Ksh,
                 const unsigned short* __restrict__ Vsh,
                 unsigned short* __restrict__ P0,    // kh=0 partial [b][2048][1024]
                 unsigned short* __restrict__ P1)    // kh=1 partial (= AO region)
{
    __shared__ float red[8192];   // 32KB reduce scratch (end only, per qi-pass)

    const int t = threadIdx.x;
    const int lane = t & 63;
    const int l31 = lane & 31;
    const int lh = lane >> 5;
    const int w = t >> 6;
    const int qh = w >> 1;     // q-slice owned (64 rows)
    const int kbl = w & 1;     // k-half owned within a 64-chunk

    // XCD-chunked bijective swizzle (512 blocks, 64 per XCD -> 4 (b,h)/XCD)
    const int bid = blockIdx.x;
    const int lb = (bid & 7) * 64 + (bid >> 3);
    const int kh = lb & 1;             // k-split half: chunks [16kh,16kh+16)
    const int qb = (lb >> 1) & 7;
    const int h = (lb >> 4) & 15;
    const int b = lb >> 8;
    const int qbase = qb * 256;
    const int kb0 = kh * 16;

    unsigned short* const PO = kh ? P1 : P0;

    const unsigned short* Kc = Ksh + (size_t)(b * 16 + h) * 131072;
    const unsigned short* Vc = Vsh + (size_t)(b * 16 + h) * 131072;

    // per-wave contiguous frag bases (chunk kb at +kb*4096)
    const unsigned short* Kw = Kc + (size_t)kbl * 2048 + lane * 8;
    const unsigned short* Vw = Vc + (size_t)kbl * 2048 + lane * 8;

    // Q fragments (loop-invariant): qf[qi][ds], rows qbase+qh*64+qi*32+l31
    fragAB qf[2][4];
#pragma unroll
    for (int qi = 0; qi < 2; ++qi)
#pragma unroll
        for (int ds = 0; ds < 4; ++ds)
            qf[qi][ds] = *(const fragAB*)(Qg
                + (size_t)(b * 2048 + qbase + qh * 64 + qi * 32 + l31) * 1024
                + h * 64 + ds * 16 + lh * 8);

    f32x16 o[2][2];
#pragma unroll
    for (int qi = 0; qi < 2; ++qi)
#pragma unroll
        for (int ni = 0; ni < 2; ++ni)
#pragma unroll
            for (int r = 0; r < 16; ++r) o[qi][ni][r] = 0.f;

    // register double-buffer: A = current, B = next
    fragAB kfA[4], vfA[4], kfB[4], vfB[4];
#pragma unroll
    for (int ds = 0; ds < 4; ++ds) kfA[ds] = *(const fragAB*)(Kw + (size_t)kb0 * 4096 + ds * 512);
#pragma unroll
    for (int j = 0; j < 4; ++j)    vfA[j]  = *(const fragAB*)(Vw + (size_t)kb0 * 4096 + j * 512);

    const int kbLast = kb0 + 15;

    auto body = [&](int kb, fragAB (&kfc)[4], fragAB (&vfc)[4],
                            fragAB (&kfn)[4], fragAB (&vfn)[4]) {
        if (kb < kbLast) {   // prefetch kb+1 into next regs (counted vmcnt, no drain)
            const size_t so = (size_t)(kb + 1) * 4096;
#pragma unroll
            for (int ds = 0; ds < 4; ++ds) kfn[ds] = *(const fragAB*)(Kw + so + ds * 512);
#pragma unroll
            for (int j = 0; j < 4; ++j)    vfn[j]  = *(const fragAB*)(Vw + so + j * 512);
        }

        // QK: st[qi] = K(own 32k) . Q(qi-th 32q)^T over d=64
        f32x16 st[2];
#pragma unroll
        for (int qi = 0; qi < 2; ++qi)
#pragma unroll
            for (int r = 0; r < 16; ++r) st[qi][r] = 0.f;
        __builtin_amdgcn_s_setprio(1);
#pragma unroll
        for (int qi = 0; qi < 2; ++qi)
#pragma unroll
            for (int ds = 0; ds < 4; ++ds)
                st[qi] = MFMA32(kfc[ds], qf[qi][ds], st[qi]);
        __builtin_amdgcn_s_setprio(0);

        // per qi: sin -> bf16 pairs -> permlane32_swap -> PV
#pragma unroll
        for (int qi = 0; qi < 2; ++qi) {
            unsigned int u[8];
#pragma unroll
            for (int i = 0; i < 8; ++i)
                u[i] = cvtpk(fsin_rev(st[qi][2 * i] * SIN_SC),
                             fsin_rev(st[qi][2 * i + 1] * SIN_SC));
            swap32(u[0], u[2]); swap32(u[1], u[3]);
            swap32(u[4], u[6]); swap32(u[5], u[7]);
            union { u32x4 u; fragAB f; } pa0, pa1;
            pa0.u = (u32x4){u[0], u[1], u[2], u[3]};
            pa1.u = (u32x4){u[4], u[5], u[6], u[7]};
            __builtin_amdgcn_s_setprio(1);
#pragma unroll
            for (int ni = 0; ni < 2; ++ni) {
                o[qi][ni] = MFMA32(pa0.f, vfc[ni], o[qi][ni]);
                o[qi][ni] = MFMA32(pa1.f, vfc[2 + ni], o[qi][ni]);
            }
            __builtin_amdgcn_s_setprio(0);
        }
    };

    for (int tt = 0; tt < 8; ++tt) {
        body(kb0 + 2 * tt,     kfA, vfA, kfB, vfB);
        body(kb0 + 2 * tt + 1, kfB, vfB, kfA, vfA);
    }

    // cross-k-half reduce, TWO PASSES over qi (32KB LDS): kbl=1 writes, kbl=0 adds+stores
#pragma unroll
    for (int qi = 0; qi < 2; ++qi) {
        if (qi) __syncthreads();   // protect red reuse between passes
        if (kbl) {
#pragma unroll
            for (int ni = 0; ni < 2; ++ni)
#pragma unroll
                for (int r = 0; r < 16; ++r)
                    red[((qh * 2 + ni) * 16 + r) * 64 + lane] = o[qi][ni][r];
        }
        __syncthreads();
        if (!kbl) {
#pragma unroll
            for (int ni = 0; ni < 2; ++ni)
#pragma unroll
                for (int r = 0; r < 16; ++r) {
                    const float v = o[qi][ni][r]
                        + red[((qh * 2 + ni) * 16 + r) * 64 + lane];
                    const int q = qbase + qh * 64 + qi * 32 + (r & 3) + 8 * (r >> 2) + 4 * lh;
                    PO[((size_t)b * 2048 + q) * 1024 + h * 64 + ni * 32 + l31] = f2bf(v);
                }
        }
    }
}

// ---------- launcher ----------
extern "C" void kernel_launch(void* const* d_in, const int* in_sizes, int n_in,
                              void* d_out, int out_size, void* d_ws, size_t ws_size,
                              hipStream_t stream) {
    (void)in_sizes; (void)n_in; (void)out_size; (void)ws_size;
    const float* x  = (const float*)d_in[0];
    const float* Wq = (const float*)d_in[1];
    const float* bq = (const float*)d_in[2];
    const float* Wk = (const float*)d_in[3];
    const float* bk = (const float*)d_in[4];
    const float* Wv = (const float*)d_in[5];
    const float* bv = (const float*)d_in[6];
    const float* Wo = (const float*)d_in[7];
    const float* bo = (const float*)d_in[8];

    char* ws = (char*)d_ws;
    unsigned short* xb    = (unsigned short*)(ws);                    // 8MB (dead after gemm_k)
    unsigned short* Wqb   = (unsigned short*)(ws + (8u  << 20));      // 2MB each (dead after gemm_k)
    unsigned short* Wkb   = (unsigned short*)(ws + (10u << 20));
    unsigned short* Wvb   = (unsigned short*)(ws + (12u << 20));
    unsigned short* Wob   = (unsigned short*)(ws + (14u << 20));      // LIVE until gemm64!
    unsigned short* Qb    = (unsigned short*)(ws + (16u << 20));      // 8MB row-major
    unsigned short* Kshuf = (unsigned short*)(ws + (24u << 20));      // 8MB frag-order
    unsigned short* Vshuf = (unsigned short*)(ws + (32u << 20));      // 8MB frag-order
    unsigned short* AO    = (unsigned short*)(ws + (40u << 20));      // 8MB row-major
    unsigned short* P0    = (unsigned short*)(ws);                    // 8MB partial kh=0 (xb region only)

    cvt_all<<<8192, 256, 0, stream>>>(x, Wq, Wk, Wv, Wo, xb, Wqb, Wkb, Wvb, Wob);

    gemm_k<<<dim3(8, 32, 3), 256, 0, stream>>>(xb, Wqb, Wkb, Wvb, bq, bk, bv,
                                               Qb, Kshuf, Vshuf);

    attn_kernel<<<512, 512, 0, stream>>>(Qb, Kshuf, Vshuf, P0, AO);

    add_bf16<<<2048, 256, 0, stream>>>(P0, AO);

    gemm64<<<dim3(8, 64), 256, 0, stream>>>(AO, Wob, bo, (float*)d_out);
}

// Round 18
// 104.090 us; speedup vs baseline: 1.0830x; 1.0830x over previous
//
#include <hip/hip_runtime.h>
#include <stdint.h>

// ---------- types ----------
typedef __attribute__((ext_vector_type(8))) __bf16 fragAB;   // 8 bf16 = 4 VGPR
typedef __attribute__((ext_vector_type(4))) float f32x4;
typedef __attribute__((ext_vector_type(16))) float f32x16;
typedef __attribute__((ext_vector_type(4))) unsigned int u32x4;

__device__ __forceinline__ unsigned short f2bf(float f) {
    union { float f; unsigned int u; } v; v.f = f;
    unsigned int u = v.u + 0x7fffu + ((v.u >> 16) & 1u);   // RNE
    return (unsigned short)(u >> 16);
}

__device__ __forceinline__ f32x4 MFMA16(fragAB a, fragAB b, f32x4 c) {
    return __builtin_amdgcn_mfma_f32_16x16x32_bf16(a, b, c, 0, 0, 0);
}
__device__ __forceinline__ f32x16 MFMA32(fragAB a, fragAB b, f32x16 c) {
    return __builtin_amdgcn_mfma_f32_32x32x16_bf16(a, b, c, 0, 0, 0);
}

// async global->LDS, 16B per lane; LDS dest = wave-uniform base + lane*16
__device__ __forceinline__ void gl16(const void* g, void* l) {
    __builtin_amdgcn_global_load_lds((const __attribute__((address_space(1))) void*)g,
                                     (__attribute__((address_space(3))) void*)l, 16, 0, 0);
}

__device__ __forceinline__ float fsin_rev(float rev) {   // sin(2*pi*rev)
    float r; asm("v_sin_f32 %0, %1" : "=v"(r) : "v"(rev)); return r;
}
__device__ __forceinline__ unsigned int cvtpk(float lo, float hi) {  // 2xbf16 RNE
    unsigned int r; asm("v_cvt_pk_bf16_f32 %0, %1, %2" : "=v"(r) : "v"(lo), "v"(hi)); return r;
}
__device__ __forceinline__ void swap32(unsigned int& a, unsigned int& b) {
    // exchanges a's lanes 32-63 with b's lanes 0-31
    asm volatile("v_permlane32_swap_b32 %0, %1" : "+v"(a), "+v"(b));
}

#define SIN_SC 0.5968310366f   // 3.75 / (2*pi)

// ---------- fused fp32 -> bf16 convert (x + 4 weights in one launch) ----------
__global__ __launch_bounds__(256) void cvt_all(
    const float* __restrict__ x,  const float* __restrict__ wq, const float* __restrict__ wk,
    const float* __restrict__ wv, const float* __restrict__ wo,
    unsigned short* __restrict__ xb,  unsigned short* __restrict__ wqb, unsigned short* __restrict__ wkb,
    unsigned short* __restrict__ wvb, unsigned short* __restrict__ wob)
{
    const int bid = blockIdx.x;
    const float* s; unsigned short* d; int off;
    if (bid < 4096)      { s = x;  d = xb;  off = bid; }
    else if (bid < 5120) { s = wq; d = wqb; off = bid - 4096; }
    else if (bid < 6144) { s = wk; d = wkb; off = bid - 5120; }
    else if (bid < 7168) { s = wv; d = wvb; off = bid - 6144; }
    else                 { s = wo; d = wob; off = bid - 7168; }
    const int i = (off * 256 + threadIdx.x) * 4;
    float4 f = *(const float4*)(s + i);
    ushort4 o;
    o.x = f2bf(f.x); o.y = f2bf(f.y); o.z = f2bf(f.z); o.w = f2bf(f.w);
    *(ushort4*)(d + i) = o;
}

// ---------- GEMM (m97 structure, 128x128): Q/K/V projections ----------
// z=0: Q row-major bf16 (unscaled). z=1: Kshuf. z=2: Vshuf (frag order).
__global__ __launch_bounds__(256, 2)
void gemm_k(const unsigned short* __restrict__ A,
            const unsigned short* __restrict__ W0, const unsigned short* __restrict__ W1,
            const unsigned short* __restrict__ W2,
            const float* __restrict__ b0, const float* __restrict__ b1, const float* __restrict__ b2,
            void* o0, void* o1, void* o2)
{
    __shared__ unsigned short As[8192];   // [128][64] linear, 16KB
    __shared__ unsigned short Ws[8192];

    const int z = blockIdx.z;
    const unsigned short* W = z == 0 ? W0 : (z == 1 ? W1 : W2);
    const float* bias        = z == 0 ? b0 : (z == 1 ? b1 : b2);
    void* out                = z == 0 ? o0 : (z == 1 ? o1 : o2);

    const int t = threadIdx.x;
    const int lane = t & 63;
    const int g = lane >> 4;
    const int c = lane & 15;
    const int w = t >> 6;
    const int wm = (w >> 1) * 64;
    const int wn = (w & 1) * 64;
    const int m0 = blockIdx.y * 128;
    const int n0 = blockIdx.x * 128;

    const int srow = lane >> 3;
    const int scol = (lane & 7) * 8;

    const f32x4 zz = {0.f, 0.f, 0.f, 0.f};
    f32x4 acc[4][4];
#pragma unroll
    for (int mi = 0; mi < 4; ++mi)
#pragma unroll
        for (int ni = 0; ni < 4; ++ni) acc[mi][ni] = zz;

    for (int kt = 0; kt < 16; ++kt) {
        const int k0 = kt * 64;
#pragma unroll
        for (int r = 0; r < 4; ++r) {
            gl16(A + (size_t)(m0 + 32 * w + 8 * r + srow) * 1024 + k0 + scol,
                 (unsigned short*)As + (w * 4 + r) * 512);
            gl16(W + (size_t)(n0 + 32 * w + 8 * r + srow) * 1024 + k0 + scol,
                 (unsigned short*)Ws + (w * 4 + r) * 512);
        }
        __syncthreads();
#pragma unroll
        for (int kk = 0; kk < 2; ++kk) {
            fragAB af[4], bfr[4];
#pragma unroll
            for (int mi = 0; mi < 4; ++mi)
                af[mi] = *(const fragAB*)((char*)As + (wm + mi * 16 + c) * 128 + kk * 64 + g * 16);
#pragma unroll
            for (int ni = 0; ni < 4; ++ni)
                bfr[ni] = *(const fragAB*)((char*)Ws + (wn + ni * 16 + c) * 128 + kk * 64 + g * 16);
#pragma unroll
            for (int mi = 0; mi < 4; ++mi)
#pragma unroll
                for (int ni = 0; ni < 4; ++ni)
                    acc[mi][ni] = MFMA16(af[mi], bfr[ni], acc[mi][ni]);
        }
        __syncthreads();
    }

    float bv[4];
#pragma unroll
    for (int ni = 0; ni < 4; ++ni) bv[ni] = bias[n0 + wn + ni * 16 + c];

    if (z == 0) {                                // Q: row-major bf16 (unscaled)
        unsigned short* C = (unsigned short*)out;
#pragma unroll
        for (int mi = 0; mi < 4; ++mi)
#pragma unroll
            for (int ni = 0; ni < 4; ++ni)
#pragma unroll
                for (int j = 0; j < 4; ++j) {
                    const int grow = m0 + wm + mi * 16 + g * 4 + j;
                    const int gcol = n0 + wn + ni * 16 + c;
                    C[(size_t)grow * 1024 + gcol] = f2bf(acc[mi][ni][j] + bv[ni]);
                }
    } else if (z == 1) {                         // Kshuf scatter (2B stores)
        unsigned short* Ksh = (unsigned short*)out;
#pragma unroll
        for (int mi = 0; mi < 4; ++mi) {
            const int s0 = m0 + wm + mi * 16 + g * 4;
            const int b_ = s0 >> 11, sr = s0 & 2047;
            const int kb = sr >> 6, kbl = (sr >> 5) & 1;
            const int l31b = (mi & 1) * 16 + g * 4;
#pragma unroll
            for (int ni = 0; ni < 4; ++ni) {
                const int n = n0 + wn + ni * 16 + c;
                const int h_ = n >> 6, d = n & 63;
                const int ds = d >> 4, e = d & 7, lhalf = (d >> 3) & 1;
                const size_t base =
                    ((((size_t)(b_ * 16 + h_) * 32 + kb) * 2 + kbl) * 4 + ds) * 512
                    + lhalf * 256 + (size_t)l31b * 8 + e;
#pragma unroll
                for (int j = 0; j < 4; ++j)
                    Ksh[base + j * 8] = f2bf(acc[mi][ni][j] + bv[ni]);
            }
        }
    } else {                                     // Vshuf scatter (8B stores)
        unsigned short* Vsh = (unsigned short*)out;
#pragma unroll
        for (int mi = 0; mi < 4; ++mi) {
            const int s0 = m0 + wm + mi * 16 + g * 4;
            const int b_ = s0 >> 11, sr = s0 & 2047;
            const int kb = sr >> 6;
            const int kslice = mi;               // (mi*16+g*4)>>4
            const int khalf = (g >> 1) & 1;
            const int e0 = (g & 1) * 4;
#pragma unroll
            for (int ni = 0; ni < 4; ++ni) {
                const int n = n0 + wn + ni * 16 + c;
                const int h_ = n >> 6;
                const int nei = ni >> 1;
                const int l31 = (ni & 1) * 16 + c;
                const size_t base =
                    ((((size_t)(b_ * 16 + h_) * 32 + kb) * 4 + kslice) * 2 + nei) * 512
                    + (size_t)(khalf * 32 + l31) * 8 + e0;
                ushort4 pk;
                pk.x = f2bf(acc[mi][ni][0] + bv[ni]);
                pk.y = f2bf(acc[mi][ni][1] + bv[ni]);
                pk.z = f2bf(acc[mi][ni][2] + bv[ni]);
                pk.w = f2bf(acc[mi][ni][3] + bv[ni]);
                *(ushort4*)(Vsh + base) = pk;
            }
        }
    }
}

// ---------- GEMM 64x128 tile, fp32 out: final projection ----------
__global__ __launch_bounds__(256, 4)
void gemm64(const unsigned short* __restrict__ A,
            const unsigned short* __restrict__ W,
            const float* __restrict__ bias, float* __restrict__ out)
{
    __shared__ unsigned short As[4096];   // [64][64]  8KB
    __shared__ unsigned short Ws[8192];   // [128][64] 16KB

    const int t = threadIdx.x;
    const int lane = t & 63;
    const int g = lane >> 4;
    const int c = lane & 15;
    const int w = t >> 6;
    const int wm = (w >> 1) * 32;
    const int wn = (w & 1) * 64;
    const int m0 = blockIdx.y * 64;
    const int n0 = blockIdx.x * 128;

    const int srow = lane >> 3;
    const int scol = (lane & 7) * 8;

    const f32x4 zz = {0.f, 0.f, 0.f, 0.f};
    f32x4 acc[2][4];
#pragma unroll
    for (int mi = 0; mi < 2; ++mi)
#pragma unroll
        for (int ni = 0; ni < 4; ++ni) acc[mi][ni] = zz;

    for (int kt = 0; kt < 16; ++kt) {
        const int k0 = kt * 64;
        gl16(A + (size_t)(m0 + 16 * w + srow) * 1024 + k0 + scol,
             (unsigned short*)As + (2 * w) * 512);
        gl16(A + (size_t)(m0 + 16 * w + 8 + srow) * 1024 + k0 + scol,
             (unsigned short*)As + (2 * w + 1) * 512);
#pragma unroll
        for (int r = 0; r < 4; ++r)
            gl16(W + (size_t)(n0 + 32 * w + 8 * r + srow) * 1024 + k0 + scol,
                 (unsigned short*)Ws + (w * 4 + r) * 512);
        __syncthreads();
#pragma unroll
        for (int kk = 0; kk < 2; ++kk) {
            fragAB af[2], bfr[4];
#pragma unroll
            for (int mi = 0; mi < 2; ++mi)
                af[mi] = *(const fragAB*)((char*)As + (wm + mi * 16 + c) * 128 + kk * 64 + g * 16);
#pragma unroll
            for (int ni = 0; ni < 4; ++ni)
                bfr[ni] = *(const fragAB*)((char*)Ws + (wn + ni * 16 + c) * 128 + kk * 64 + g * 16);
#pragma unroll
            for (int mi = 0; mi < 2; ++mi)
#pragma unroll
                for (int ni = 0; ni < 4; ++ni)
                    acc[mi][ni] = MFMA16(af[mi], bfr[ni], acc[mi][ni]);
        }
        __syncthreads();
    }

#pragma unroll
    for (int ni = 0; ni < 4; ++ni) {
        const float bv = bias[n0 + wn + ni * 16 + c];
#pragma unroll
        for (int mi = 0; mi < 2; ++mi)
#pragma unroll
            for (int j = 0; j < 4; ++j) {
                const int grow = m0 + wm + mi * 16 + g * 4 + j;
                const int gcol = n0 + wn + ni * 16 + c;
                out[(size_t)grow * 1024 + gcol] = acc[mi][ni][j] + bv;
            }
    }
}

// ---------- fused sine attention (R10 best): barrier-free, all-global frag loads ----------
// QBLK=256, 8 waves = 4 q-slices(64 rows) x 2 k-halves. Grid 256 (1 block/CU),
// XCD-chunked (4 (b,h)/XCD = 2MB K/V -> L2-resident). Reg double-buffer one iter
// ahead (counted vmcnt, never drained). No __syncthreads in main loop.
__global__ __launch_bounds__(512, 2)
void attn_kernel(const unsigned short* __restrict__ Qg,
                 const unsigned short* __restrict__ Ksh,
                 const unsigned short* __restrict__ Vsh,
                 unsigned short* __restrict__ AO)
{
    __shared__ float red[16384];   // 64KB reduce scratch (end only)

    const int t = threadIdx.x;
    const int lane = t & 63;
    const int l31 = lane & 31;
    const int lh = lane >> 5;
    const int w = t >> 6;
    const int qh = w >> 1;     // q-slice owned (64 rows)
    const int kbl = w & 1;     // k-half owned (32 of 64)

    // XCD-chunked bijective swizzle (256 blocks, 32 per XCD -> 4 (b,h) pairs/XCD)
    const int bid = blockIdx.x;
    const int lb = (bid & 7) * 32 + (bid >> 3);
    const int qb = lb & 7;
    const int h = (lb >> 3) & 15;
    const int b = lb >> 7;
    const int qbase = qb * 256;

    const unsigned short* Kc = Ksh + (size_t)(b * 16 + h) * 131072;
    const unsigned short* Vc = Vsh + (size_t)(b * 16 + h) * 131072;

    // per-wave contiguous frag bases
    const unsigned short* Kw = Kc + (size_t)kbl * 2048 + lane * 8;       // + kb*4096 + ds*512
    const unsigned short* Vw = Vc + (size_t)kbl * 2048 + lane * 8;       // + kb*4096 + j*512

    // Q fragments (loop-invariant): qf[qi][ds], rows qbase+qh*64+qi*32+l31
    fragAB qf[2][4];
#pragma unroll
    for (int qi = 0; qi < 2; ++qi)
#pragma unroll
        for (int ds = 0; ds < 4; ++ds)
            qf[qi][ds] = *(const fragAB*)(Qg
                + (size_t)(b * 2048 + qbase + qh * 64 + qi * 32 + l31) * 1024
                + h * 64 + ds * 16 + lh * 8);

    f32x16 o[2][2];
#pragma unroll
    for (int qi = 0; qi < 2; ++qi)
#pragma unroll
        for (int ni = 0; ni < 2; ++ni)
#pragma unroll
            for (int r = 0; r < 16; ++r) o[qi][ni][r] = 0.f;

    // register double-buffer: A = current, B = next
    fragAB kfA[4], vfA[4], kfB[4], vfB[4];
#pragma unroll
    for (int ds = 0; ds < 4; ++ds) kfA[ds] = *(const fragAB*)(Kw + ds * 512);
#pragma unroll
    for (int j = 0; j < 4; ++j)    vfA[j]  = *(const fragAB*)(Vw + j * 512);

    auto body = [&](int kb, fragAB (&kfc)[4], fragAB (&vfc)[4],
                            fragAB (&kfn)[4], fragAB (&vfn)[4]) {
        if (kb < 31) {   // prefetch kb+1 into next regs (counted vmcnt, no drain)
            const size_t so = (size_t)(kb + 1) * 4096;
#pragma unroll
            for (int ds = 0; ds < 4; ++ds) kfn[ds] = *(const fragAB*)(Kw + so + ds * 512);
#pragma unroll
            for (int j = 0; j < 4; ++j)    vfn[j]  = *(const fragAB*)(Vw + so + j * 512);
        }

        // QK: st[qi] = K(own 32k) . Q(qi-th 32q)^T over d=64
        f32x16 st[2];
#pragma unroll
        for (int qi = 0; qi < 2; ++qi)
#pragma unroll
            for (int r = 0; r < 16; ++r) st[qi][r] = 0.f;
        __builtin_amdgcn_s_setprio(1);
#pragma unroll
        for (int qi = 0; qi < 2; ++qi)
#pragma unroll
            for (int ds = 0; ds < 4; ++ds)
                st[qi] = MFMA32(kfc[ds], qf[qi][ds], st[qi]);
        __builtin_amdgcn_s_setprio(0);

        // per qi: sin -> bf16 pairs -> permlane32_swap -> PV
#pragma unroll
        for (int qi = 0; qi < 2; ++qi) {
            unsigned int u[8];
#pragma unroll
            for (int i = 0; i < 8; ++i)
                u[i] = cvtpk(fsin_rev(st[qi][2 * i] * SIN_SC),
                             fsin_rev(st[qi][2 * i + 1] * SIN_SC));
            swap32(u[0], u[2]); swap32(u[1], u[3]);
            swap32(u[4], u[6]); swap32(u[5], u[7]);
            union { u32x4 u; fragAB f; } pa0, pa1;
            pa0.u = (u32x4){u[0], u[1], u[2], u[3]};
            pa1.u = (u32x4){u[4], u[5], u[6], u[7]};
            __builtin_amdgcn_s_setprio(1);
#pragma unroll
            for (int ni = 0; ni < 2; ++ni) {
                o[qi][ni] = MFMA32(pa0.f, vfc[ni], o[qi][ni]);
                o[qi][ni] = MFMA32(pa1.f, vfc[2 + ni], o[qi][ni]);
            }
            __builtin_amdgcn_s_setprio(0);
        }
    };

    for (int tt = 0; tt < 16; ++tt) {
        body(2 * tt,     kfA, vfA, kfB, vfB);
        body(2 * tt + 1, kfB, vfB, kfA, vfA);
    }

    // cross-k-half reduce: kbl=1 waves write partial O, kbl=0 waves add + store
    if (kbl) {
#pragma unroll
        for (int qi = 0; qi < 2; ++qi)
#pragma unroll
            for (int ni = 0; ni < 2; ++ni)
#pragma unroll
                for (int r = 0; r < 16; ++r)
                    red[(((qh * 2 + qi) * 2 + ni) * 16 + r) * 64 + lane] = o[qi][ni][r];
    }
    __syncthreads();
    if (!kbl) {
#pragma unroll
        for (int qi = 0; qi < 2; ++qi)
#pragma unroll
            for (int ni = 0; ni < 2; ++ni)
#pragma unroll
                for (int r = 0; r < 16; ++r) {
                    const float v = o[qi][ni][r]
                        + red[(((qh * 2 + qi) * 2 + ni) * 16 + r) * 64 + lane];
                    const int q = qbase + qh * 64 + qi * 32 + (r & 3) + 8 * (r >> 2) + 4 * lh;
                    AO[(size_t)(b * 2048 + q) * 1024 + h * 64 + ni * 32 + l31] = f2bf(v);
                }
    }
}

// ---------- launcher ----------
extern "C" void kernel_launch(void* const* d_in, const int* in_sizes, int n_in,
                              void* d_out, int out_size, void* d_ws, size_t ws_size,
                              hipStream_t stream) {
    (void)in_sizes; (void)n_in; (void)out_size; (void)ws_size;
    const float* x  = (const float*)d_in[0];
    const float* Wq = (const float*)d_in[1];
    const float* bq = (const float*)d_in[2];
    const float* Wk = (const float*)d_in[3];
    const float* bk = (const float*)d_in[4];
    const float* Wv = (const float*)d_in[5];
    const float* bv = (const float*)d_in[6];
    const float* Wo = (const float*)d_in[7];
    const float* bo = (const float*)d_in[8];

    char* ws = (char*)d_ws;
    unsigned short* xb    = (unsigned short*)(ws);                    // 8MB
    unsigned short* Wqb   = (unsigned short*)(ws + (8u  << 20));      // 2MB each
    unsigned short* Wkb   = (unsigned short*)(ws + (10u << 20));
    unsigned short* Wvb   = (unsigned short*)(ws + (12u << 20));
    unsigned short* Wob   = (unsigned short*)(ws + (14u << 20));
    unsigned short* Qb    = (unsigned short*)(ws + (16u << 20));      // 8MB row-major
    unsigned short* Kshuf = (unsigned short*)(ws + (24u << 20));      // 8MB frag-order
    unsigned short* Vshuf = (unsigned short*)(ws + (32u << 20));      // 8MB frag-order
    unsigned short* AO    = (unsigned short*)(ws + (40u << 20));      // 8MB row-major

    cvt_all<<<8192, 256, 0, stream>>>(x, Wq, Wk, Wv, Wo, xb, Wqb, Wkb, Wvb, Wob);

    gemm_k<<<dim3(8, 32, 3), 256, 0, stream>>>(xb, Wqb, Wkb, Wvb, bq, bk, bv,
                                               Qb, Kshuf, Vshuf);

    attn_kernel<<<256, 512, 0, stream>>>(Qb, Kshuf, Vshuf, AO);

    gemm64<<<dim3(8, 64), 256, 0, stream>>>(AO, Wob, bo, (float*)d_out);
}